// Round 11
// baseline (224.654 us; speedup 1.0000x reference)
//
#include <hip/hip_runtime.h>
#include <math.h>

#define TOTAL   8192
#define GENES   5000
#define NDS     64          // points per cloud
#define NB      128         // TOTAL / NDS
#define NSHARED 128
#define KC      32          // K-chunk staged in LDS (32: fits 4 blocks/CU)

// ws layout (floats): [0]=gene acc, [1]=cell acc, [32..35]=zero pad for tail,
// grams start at GRAM_OFF
#define GRAM_OFF 64

typedef __attribute__((ext_vector_type(8)))  short        short8;
typedef __attribute__((ext_vector_type(4)))  unsigned int uint4v;
typedef __attribute__((ext_vector_type(16))) float        f32x16;

typedef const __attribute__((address_space(1))) void* GPTR;
typedef __attribute__((address_space(3))) void*       LPTR;

// DMA global->LDS, 16B per lane, no VGPR transit (spill-proof staging)
#define GLOAD16(gp, lp) \
    __builtin_amdgcn_global_load_lds((GPTR)(gp), (LPTR)(lp), 16, 0, 0)

__global__ __launch_bounds__(64) void k_zero(float* ws) {
    ws[threadIdx.x] = 0.0f;
}

// ---- fp32 -> bf16 round-half-up, packed pairwise. hh-only MFMA: verified
//      round 9/10, absmax ~0 vs 3.6e-2 threshold. ----
static __device__ inline unsigned int hpack2(float f0, float f1) {
    const unsigned int u0 = __builtin_bit_cast(unsigned int, f0) + 0x8000u;
    const unsigned int u1 = __builtin_bit_cast(unsigned int, f1) + 0x8000u;
    return (u1 & 0xFFFF0000u) | (u0 >> 16);
}
// read 8 consecutive logical fp32 (two 16B slots, XOR-swizzled) -> bf16x8
static __device__ inline short8 ldcvt_h(const float* base, int sw, int c0) {
    const float4 a = *(const float4*)(base + (((c0    ) ^ sw) << 2));
    const float4 b = *(const float4*)(base + (((c0 + 1) ^ sw) << 2));
    uint4v hv;
    hv[0] = hpack2(a.x, a.y); hv[1] = hpack2(a.z, a.w);
    hv[2] = hpack2(b.x, b.y); hv[3] = hpack2(b.z, b.w);
    return __builtin_bit_cast(short8, hv);
}

// ---------------------------------------------------------------------------
// K1: partial Grams per (batch, K-slice). Round-11 lever: OCCUPANCY.
// KC=32 (LDS 32 KB/block) + splitD=8 (grid 1024) -> 4 blocks/CU, 16 waves/CU
// (rounds 8-10 were pinned at 2 blocks/CU, all pipes <20%, latency-bound;
// drain-0 vs counted-vmcnt A/B'd identical -> scheduling was not the limit).
// Staging = global_load_lds DMA of raw fp32, double-buffered, counted vmcnt.
// KC=32 swizzle space is 8 slots -> fragment reads are 4-way bank-conflicted
// (1.58x on a non-critical pipe; accepted).
// grams[(b*splitD + c)][m][64*64], m: 0=xy, 1=xx, 2=yy
// ---------------------------------------------------------------------------
__global__ __launch_bounds__(256, 4)
void k_gene_gram_mfma(const float* __restrict__ X, const float* __restrict__ Y,
                      const float* __restrict__ zsrc,
                      float* __restrict__ grams, int splitD, int Dper) {
    const int blk = blockIdx.x;
    const int b = blk / splitD, c = blk % splitD;
    const int d0 = c * Dper;
    const int d1 = min(GENES, d0 + Dper);

    const float* __restrict__ xb = X + (size_t)b * NDS * GENES;
    const float* __restrict__ yb = Y + (size_t)b * NDS * GENES;

    __shared__ __align__(16) float sX[2 * NDS * KC];   // 16 KB raw fp32
    __shared__ __align__(16) float sY[2 * NDS * KC];   // 16 KB

    const int t    = threadIdx.x;
    const int lane = t & 63;
    const int w    = t >> 6;               // wave 0..3
    const int qr   = w >> 1, qc = w & 1;   // 32x32 output quadrant
    const int lm   = lane & 31;
    const int kh2  = (lane >> 5) << 1;     // k-half offset in 16B slots (0 / 2)

    const int mr  = (qr << 5) + lm;        // A-side row
    const int mc  = (qc << 5) + lm;        // B-side row (Gram col)
    const int swr = mr & 7, swc = mc & 7;  // 8-slot swizzle space at KC=32

    // ---- staging geometry: wave w stages rows [16w,16w+16), 2 instrs/array ----
    const int s8   = lane & 7;             // 16B slot this lane fills (row=8 slots)
    const int rsub = lane >> 3;            // row within 8-row group
    const int rA = (w << 4) + rsub;        // rows w*16 + 0..7
    const int rB = rA + 8;                 // rows w*16 + 8..15
    // pre-swizzled source column (floats; add chunk base dd at use)
    const int cA = (s8 ^ (rA & 7)) << 2;
    const int cB = (s8 ^ (rB & 7)) << 2;
    const float* gxA = xb + (size_t)rA * GENES + cA;
    const float* gxB = xb + (size_t)rB * GENES + cB;
    const float* gyA = yb + (size_t)rA * GENES + cA;
    const float* gyB = yb + (size_t)rB * GENES + cB;
    // uniform LDS float offsets (instruction bases; HW adds lane*16B)
    const int lA = (w << 4) * KC;
    const int lB = lA + 8 * KC;

// exactly 4 gload_lds instructions per wave -> vmcnt counts below depend on it
#define STAGEBUF(bofs, dd) do {                                               \
    const float* pxA = ((dd) + cA + 4 <= d1) ? gxA + (dd) : zsrc;             \
    const float* pxB = ((dd) + cB + 4 <= d1) ? gxB + (dd) : zsrc;             \
    const float* pyA = ((dd) + cA + 4 <= d1) ? gyA + (dd) : zsrc;             \
    const float* pyB = ((dd) + cB + 4 <= d1) ? gyB + (dd) : zsrc;             \
    GLOAD16(pxA, sX + (bofs) + lA);                                           \
    GLOAD16(pxB, sX + (bofs) + lB);                                           \
    GLOAD16(pyA, sY + (bofs) + lA);                                           \
    GLOAD16(pyB, sY + (bofs) + lB);                                           \
} while (0)

    f32x16 axy = {0,0,0,0,0,0,0,0,0,0,0,0,0,0,0,0};
    f32x16 axx = {0,0,0,0,0,0,0,0,0,0,0,0,0,0,0,0};
    f32x16 ayy = {0,0,0,0,0,0,0,0,0,0,0,0,0,0,0,0};

    const int nchunks = (d1 - d0 + KC - 1) / KC;

    STAGEBUF(0, d0);          // prologue: chunk 0 -> buf 0 (4 outstanding)

    for (int ci = 0; ci < nchunks; ++ci) {
        const int bofs = (ci & 1) * (NDS * KC);

        // issue next chunk into the other buffer (safe: end-of-iteration
        // barrier of ci-1), then wait for ONLY the current chunk's 4 loads.
        if (ci + 1 < nchunks) {
            STAGEBUF(((ci + 1) & 1) * (NDS * KC), d0 + (ci + 1) * KC);
            __builtin_amdgcn_sched_barrier(0);
            asm volatile("s_waitcnt vmcnt(4)" ::: "memory");
        } else {
            asm volatile("s_waitcnt vmcnt(0)" ::: "memory");
        }
        __builtin_amdgcn_sched_barrier(0);
        __builtin_amdgcn_s_barrier();          // all waves' chunk-ci staging visible
        __builtin_amdgcn_sched_barrier(0);

        const float* xrow = sX + bofs + mr * KC;
        const float* yrow = sY + bofs + mr * KC;
        const float* xcol = sX + bofs + mc * KC;
        const float* ycol = sY + bofs + mc * KC;
#pragma unroll
        for (int ks = 0; ks < KC / 16; ++ks) {
            const int c0 = (ks << 2) + kh2;
            const short8 xr = ldcvt_h(xrow, swr, c0);
            const short8 yr = ldcvt_h(yrow, swr, c0);
            const short8 xc = ldcvt_h(xcol, swc, c0);
            const short8 yc = ldcvt_h(ycol, swc, c0);
            axy = __builtin_amdgcn_mfma_f32_32x32x16_bf16(xr, yc, axy, 0, 0, 0);
            axx = __builtin_amdgcn_mfma_f32_32x32x16_bf16(xr, xc, axx, 0, 0, 0);
            ayy = __builtin_amdgcn_mfma_f32_32x32x16_bf16(yr, yc, ayy, 0, 0, 0);
        }

        // my LDS reads retired; barrier so next iter may overwrite buf[ci&1].
        __builtin_amdgcn_sched_barrier(0);
        asm volatile("s_waitcnt lgkmcnt(0)" ::: "memory");
        __builtin_amdgcn_s_barrier();
        __builtin_amdgcn_sched_barrier(0);
    }
#undef STAGEBUF

    // ---- writeout: verified 32x32 C/D layout: col=lane&31,
    //      row=(reg&3)+8*(reg>>2)+4*(lane>>5) ----
    float* g = grams + (size_t)(b * splitD + c) * 3 * 4096;
    const int col = (qc << 5) + lm;
#pragma unroll
    for (int r = 0; r < 16; ++r) {
        const int row = (qr << 5) + (r & 3) + ((r >> 2) << 3) + ((lane >> 5) << 2);
        g[0 * 4096 + row * 64 + col] = axy[r];
        g[1 * 4096 + row * 64 + col] = axx[r];
        g[2 * 4096 + row * 64 + col] = ayy[r];
    }
}

// ---------------------------------------------------------------------------
// K2: per batch — reduce Gram partials, distances, mean, accumulate.
// ---------------------------------------------------------------------------
__global__ __launch_bounds__(256) void k_gene_dist(const float* __restrict__ grams,
                                                   float* __restrict__ acc,
                                                   int splitD) {
    const int b = blockIdx.x, t = threadIdx.x;
    __shared__ __align__(16) float G[3 * 4096];   // 48 KB
    __shared__ float red[4];

    for (int m = 0; m < 3; ++m) {
#pragma unroll
        for (int k = 0; k < 16; ++k) {
            const int e = t + 256 * k;
            float s = 0.f;
            for (int c = 0; c < splitD; ++c)
                s += grams[((size_t)(b * splitD + c) * 3 + m) * 4096 + e];
            G[m * 4096 + e] = s;
        }
    }
    __syncthreads();

    float local = 0.f;
#pragma unroll
    for (int k = 0; k < 16; ++k) {
        const int e = t + 256 * k;
        const int i = e >> 6, j = e & 63;
        const float gxy = G[e];
        const float gxx = G[4096 + e];
        const float gyy = G[8192 + e];
        const float nxi = G[4096 + i * 65], nxj = G[4096 + j * 65];
        const float nyi = G[8192 + i * 65], nyj = G[8192 + j * 65];
        const float dxy = sqrtf(fmaxf(nxi + nyj - 2.f * gxy, 0.f));
        const float dxx = sqrtf(fmaxf(nxi + nxj - 2.f * gxx, 0.f));
        const float dyy = sqrtf(fmaxf(nyi + nyj - 2.f * gyy, 0.f));
        local += dxy - 0.5f * (dxx + dyy);
    }
#pragma unroll
    for (int off = 32; off; off >>= 1) local += __shfl_down(local, off);
    if ((t & 63) == 0) red[t >> 6] = local;
    __syncthreads();
    if (t == 0) {
        const float bl = red[0] + red[1] + red[2] + red[3];
        atomicAdd(acc, bl * (1.0f / (4096.0f * (float)NB)));
    }
}

// ---------------------------------------------------------------------------
// K3: cell-level — one block per shared gene s. Clouds: 64 points x 128 dims.
// fp32 vector-FMA path (exact).
// ---------------------------------------------------------------------------
__global__ __launch_bounds__(256) void k_cell(const float* __restrict__ X,
                                              const float* __restrict__ Y,
                                              float* __restrict__ acc) {
    const int s   = blockIdx.x;
    const int col = GENES - NSHARED + s;
    const int t   = threadIdx.x;

    __shared__ __align__(16) float lds[16384];    // 64 KB

#pragma unroll
    for (int k = 0; k < 32; ++k) {
        const int idx = t + 256 * k;              // = b*64 + n, 0..8191
        lds[idx]        = X[(size_t)idx * GENES + col];
        lds[8192 + idx] = Y[(size_t)idx * GENES + col];
    }
    __syncthreads();

    const int ti = t & 15, tj = t >> 4;
    const int i0 = ti << 2, j0 = tj << 2;
    float axy[4][4] = {{0}}, axx[4][4] = {{0}}, ayy[4][4] = {{0}};

#pragma unroll 4
    for (int bb = 0; bb < NB; ++bb) {
        const float4 xi4 = *(const float4*)(lds + bb * 64 + i0);
        const float4 xj4 = *(const float4*)(lds + bb * 64 + j0);
        const float4 yi4 = *(const float4*)(lds + 8192 + bb * 64 + i0);
        const float4 yj4 = *(const float4*)(lds + 8192 + bb * 64 + j0);
        const float* xi = &xi4.x;
        const float* xj = &xj4.x;
        const float* yi = &yi4.x;
        const float* yj = &yj4.x;
#pragma unroll
        for (int ii = 0; ii < 4; ++ii) {
#pragma unroll
            for (int jj = 0; jj < 4; ++jj) {
                axy[ii][jj] = fmaf(xi[ii], yj[jj], axy[ii][jj]);
                axx[ii][jj] = fmaf(xi[ii], xj[jj], axx[ii][jj]);
                ayy[ii][jj] = fmaf(yi[ii], yj[jj], ayy[ii][jj]);
            }
        }
    }
    __syncthreads();
#pragma unroll
    for (int ii = 0; ii < 4; ++ii) {
        float4 v;
        v.x = axy[ii][0]; v.y = axy[ii][1]; v.z = axy[ii][2]; v.w = axy[ii][3];
        *(float4*)(lds + 0 * 4096 + (i0 + ii) * 64 + j0) = v;
        v.x = axx[ii][0]; v.y = axx[ii][1]; v.z = axx[ii][2]; v.w = axx[ii][3];
        *(float4*)(lds + 1 * 4096 + (i0 + ii) * 64 + j0) = v;
        v.x = ayy[ii][0]; v.y = ayy[ii][1]; v.z = ayy[ii][2]; v.w = ayy[ii][3];
        *(float4*)(lds + 2 * 4096 + (i0 + ii) * 64 + j0) = v;
    }
    __syncthreads();

    float local = 0.f;
#pragma unroll
    for (int k = 0; k < 16; ++k) {
        const int e = t + 256 * k;
        const int i = e >> 6, j = e & 63;
        const float gxy = lds[e];
        const float gxx = lds[4096 + e];
        const float gyy = lds[8192 + e];
        const float nxi = lds[4096 + i * 65], nxj = lds[4096 + j * 65];
        const float nyi = lds[8192 + i * 65], nyj = lds[8192 + j * 65];
        const float dxy = sqrtf(fmaxf(nxi + nyj - 2.f * gxy, 0.f));
        const float dxx = sqrtf(fmaxf(nxi + nxj - 2.f * gxx, 0.f));
        const float dyy = sqrtf(fmaxf(nyi + nyj - 2.f * gyy, 0.f));
        local += dxy - 0.5f * (dxx + dyy);
    }
#pragma unroll
    for (int off = 32; off; off >>= 1) local += __shfl_down(local, off);
    __syncthreads();
    if ((t & 63) == 0) lds[t >> 6] = local;
    __syncthreads();
    if (t == 0) {
        const float bl = lds[0] + lds[1] + lds[2] + lds[3];
        atomicAdd(acc, bl * (1.0f / (4096.0f * (float)NSHARED)));
    }
}

__global__ void k_final(const float* __restrict__ acc, float* __restrict__ out) {
    out[0] = acc[0] + acc[1];
}

extern "C" void kernel_launch(void* const* d_in, const int* in_sizes, int n_in,
                              void* d_out, int out_size, void* d_ws, size_t ws_size,
                              hipStream_t stream) {
    const float* X = (const float*)d_in[0];
    const float* Y = (const float*)d_in[1];
    float* out = (float*)d_out;
    float* ws  = (float*)d_ws;

    // prefer splitD=8: grid 1024 -> 4 blocks/CU (round-4 WRITE_SIZE=49MB
    // proved ws >= 50.4MB, so 8 should fit; fall back if not)
    int splitD = 2;
    const int cand[3] = {8, 4, 2};
    for (int i = 0; i < 3; ++i) {
        if (((size_t)GRAM_OFF + (size_t)cand[i] * NB * 3 * 4096) * sizeof(float)
            <= ws_size) { splitD = cand[i]; break; }
    }
    const int chunks = (GENES + KC - 1) / KC;            // 157 at KC=32
    const int cper   = (chunks + splitD - 1) / splitD;   // chunks per slice
    const int Dper   = cper * KC;                        // multiple of KC

    float* acc   = ws;
    float* zsrc  = ws + 32;          // 16B of zeros (k_zero covers [0,64))
    float* grams = ws + GRAM_OFF;

    hipLaunchKernelGGL(k_zero,           dim3(1),           dim3(64),  0, stream, ws);
    hipLaunchKernelGGL(k_gene_gram_mfma, dim3(NB * splitD), dim3(256), 0, stream,
                       X, Y, zsrc, grams, splitD, Dper);
    hipLaunchKernelGGL(k_gene_dist,      dim3(NB),          dim3(256), 0, stream,
                       grams, acc + 0, splitD);
    hipLaunchKernelGGL(k_cell,           dim3(NSHARED),     dim3(256), 0, stream,
                       X, Y, acc + 1);
    hipLaunchKernelGGL(k_final,          dim3(1),           dim3(1),   0, stream, acc, out);
}

// Round 12
// 204.853 us; speedup vs baseline: 1.0967x; 1.0967x over previous
//
#include <hip/hip_runtime.h>
#include <math.h>

#define TOTAL   8192
#define GENES   5000
#define NDS     64          // points per cloud
#define NB      128         // TOTAL / NDS
#define NSHARED 128
#define KC      256         // K-chunk staged in LDS (1KB/row reads: DRAM-friendly)

// ws layout (floats): [0]=gene acc, [1]=cell acc, grams start at GRAM_OFF
#define GRAM_OFF 64

typedef __attribute__((ext_vector_type(8)))  short        short8;
typedef __attribute__((ext_vector_type(16))) float        f32x16;

__global__ __launch_bounds__(64) void k_zero(float* ws) {
    ws[threadIdx.x] = 0.0f;
}

// ---- fp32 -> bf16 round-half-up, packed pairwise. hh-only MFMA verified
//      rounds 9-11: absmax ~0 vs 3.6e-2 threshold. ----
static __device__ inline unsigned int hpack2(float f0, float f1) {
    const unsigned int u0 = __builtin_bit_cast(unsigned int, f0) + 0x8000u;
    const unsigned int u1 = __builtin_bit_cast(unsigned int, f1) + 0x8000u;
    return (u1 & 0xFFFF0000u) | (u0 >> 16);
}

// one row-chunk load: lane reads float4 at col = dd + lane*4 -> the WAVE reads
// 1KB CONTIGUOUS from this row (the round-12 lever: 256B scattered reads were
// capping streaming at ~1.5TB/s across rounds 2-11, invariant to occupancy
// and scheduling).
static __device__ inline float4 ldrow(const float* __restrict__ p, int r,
                                      int col, int d1) {
    float4 v = {0.f, 0.f, 0.f, 0.f};
    if (col + 4 <= d1) v = *(const float4*)(p + (size_t)r * GENES + col);
    return v;
}

// convert float4 -> 4 bf16 (8B), write at XOR-swizzled slot. Write side of
// the swizzle pair; frag() below uses the same slot ^ (row&31).
static __device__ inline void wr_row(unsigned short* s, int r, int lane, float4 v) {
    const unsigned int a = hpack2(v.x, v.y);
    const unsigned int b = hpack2(v.z, v.w);
    const int slot = (lane >> 1) ^ (r & 31);                  // 16B slot 0..31
    const int off  = r * KC + slot * 8 + (lane & 1) * 4;      // ushort units
    uint2 u; u.x = a; u.y = b;
    *(uint2*)&s[off] = u;
}

// stage 8 rows of one array (8 named float4s in flight; all by-value — no
// address-taking, the round-5/6 alloca trap)
static __device__ inline void stage8(const float* __restrict__ p,
                                     unsigned short* s, int rbase, int lane,
                                     int col, int d1) {
    const float4 v0 = ldrow(p, rbase + 0, col, d1);
    const float4 v1 = ldrow(p, rbase + 1, col, d1);
    const float4 v2 = ldrow(p, rbase + 2, col, d1);
    const float4 v3 = ldrow(p, rbase + 3, col, d1);
    const float4 v4 = ldrow(p, rbase + 4, col, d1);
    const float4 v5 = ldrow(p, rbase + 5, col, d1);
    const float4 v6 = ldrow(p, rbase + 6, col, d1);
    const float4 v7 = ldrow(p, rbase + 7, col, d1);
    wr_row(s, rbase + 0, lane, v0);
    wr_row(s, rbase + 1, lane, v1);
    wr_row(s, rbase + 2, lane, v2);
    wr_row(s, rbase + 3, lane, v3);
    wr_row(s, rbase + 4, lane, v4);
    wr_row(s, rbase + 5, lane, v5);
    wr_row(s, rbase + 6, lane, v6);
    wr_row(s, rbase + 7, lane, v7);
}

// MFMA A/B fragment: 16B of row at K-step ks, k-half kh, swizzle-matched
static __device__ inline short8 frag(const unsigned short* s, int row,
                                     int ks, int kh) {
    const int slot = ((ks << 1) + kh) ^ (row & 31);
    return *(const short8*)&s[row * KC + slot * 8];
}

// ---------------------------------------------------------------------------
// K1: partial Grams per (batch, K-slice). KC=256, bf16 staged in LDS via
// register path (convert-on-stage), 1KB-contiguous global reads, single
// 64KB buffer (2 blocks/CU interleave stage/compute), 3 MFMAs per K=16.
// grams[(b*splitD + c)][m][64*64], m: 0=xy, 1=xx, 2=yy
// ---------------------------------------------------------------------------
__global__ __launch_bounds__(256, 2)
void k_gene_gram_mfma(const float* __restrict__ X, const float* __restrict__ Y,
                      float* __restrict__ grams, int splitD, int Dper) {
    const int blk = blockIdx.x;
    const int b = blk / splitD, c = blk % splitD;
    const int d0 = c * Dper;
    const int d1 = min(GENES, d0 + Dper);

    const float* __restrict__ xb = X + (size_t)b * NDS * GENES;
    const float* __restrict__ yb = Y + (size_t)b * NDS * GENES;

    __shared__ __align__(16) unsigned short sX[NDS * KC];   // 32 KB bf16
    __shared__ __align__(16) unsigned short sY[NDS * KC];   // 32 KB bf16

    const int t    = threadIdx.x;
    const int lane = t & 63;
    const int w    = t >> 6;               // wave 0..3
    const int qr   = w >> 1, qc = w & 1;   // 32x32 output quadrant
    const int lm   = lane & 31;
    const int kh   = lane >> 5;            // k-half 0/1

    const int mr = (qr << 5) + lm;         // A-side row
    const int mc = (qc << 5) + lm;         // B-side row (Gram col)

    const int r0 = w << 4;                 // this wave stages rows r0..r0+15
    const int le = lane << 2;              // lane's float offset within chunk

    f32x16 axy = {0,0,0,0,0,0,0,0,0,0,0,0,0,0,0,0};
    f32x16 axx = {0,0,0,0,0,0,0,0,0,0,0,0,0,0,0,0};
    f32x16 ayy = {0,0,0,0,0,0,0,0,0,0,0,0,0,0,0,0};

    const int nchunks = (d1 - d0 + KC - 1) / KC;

    for (int ci = 0; ci < nchunks; ++ci) {
        const int dd  = d0 + ci * KC;
        const int col = dd + le;

        // ---- stage chunk (1KB-contiguous reads, bf16 convert, swizzled) ----
        stage8(xb, sX, r0,     lane, col, d1);
        stage8(xb, sX, r0 + 8, lane, col, d1);
        stage8(yb, sY, r0,     lane, col, d1);
        stage8(yb, sY, r0 + 8, lane, col, d1);
        __syncthreads();                     // staging visible

        // ---- compute: 16 K=16 steps, 3 MFMAs each ----
#pragma unroll
        for (int ks = 0; ks < KC / 16; ++ks) {
            const short8 xr = frag(sX, mr, ks, kh);
            const short8 yr = frag(sY, mr, ks, kh);
            const short8 xc = frag(sX, mc, ks, kh);
            const short8 yc = frag(sY, mc, ks, kh);
            axy = __builtin_amdgcn_mfma_f32_32x32x16_bf16(xr, yc, axy, 0, 0, 0);
            axx = __builtin_amdgcn_mfma_f32_32x32x16_bf16(xr, xc, axx, 0, 0, 0);
            ayy = __builtin_amdgcn_mfma_f32_32x32x16_bf16(yr, yc, ayy, 0, 0, 0);
        }
        __syncthreads();                     // compute done; buffer reusable
    }

    // ---- writeout: verified 32x32 C/D layout: col=lane&31,
    //      row=(reg&3)+8*(reg>>2)+4*(lane>>5) ----
    float* g = grams + (size_t)(b * splitD + c) * 3 * 4096;
    const int col = (qc << 5) + lm;
#pragma unroll
    for (int r = 0; r < 16; ++r) {
        const int row = (qr << 5) + (r & 3) + ((r >> 2) << 3) + ((lane >> 5) << 2);
        g[0 * 4096 + row * 64 + col] = axy[r];
        g[1 * 4096 + row * 64 + col] = axx[r];
        g[2 * 4096 + row * 64 + col] = ayy[r];
    }
}

// ---------------------------------------------------------------------------
// K2: per batch — reduce Gram partials, distances, mean, accumulate.
// ---------------------------------------------------------------------------
__global__ __launch_bounds__(256) void k_gene_dist(const float* __restrict__ grams,
                                                   float* __restrict__ acc,
                                                   int splitD) {
    const int b = blockIdx.x, t = threadIdx.x;
    __shared__ __align__(16) float G[3 * 4096];   // 48 KB
    __shared__ float red[4];

    for (int m = 0; m < 3; ++m) {
#pragma unroll
        for (int k = 0; k < 16; ++k) {
            const int e = t + 256 * k;
            float s = 0.f;
            for (int c = 0; c < splitD; ++c)
                s += grams[((size_t)(b * splitD + c) * 3 + m) * 4096 + e];
            G[m * 4096 + e] = s;
        }
    }
    __syncthreads();

    float local = 0.f;
#pragma unroll
    for (int k = 0; k < 16; ++k) {
        const int e = t + 256 * k;
        const int i = e >> 6, j = e & 63;
        const float gxy = G[e];
        const float gxx = G[4096 + e];
        const float gyy = G[8192 + e];
        const float nxi = G[4096 + i * 65], nxj = G[4096 + j * 65];
        const float nyi = G[8192 + i * 65], nyj = G[8192 + j * 65];
        const float dxy = sqrtf(fmaxf(nxi + nyj - 2.f * gxy, 0.f));
        const float dxx = sqrtf(fmaxf(nxi + nxj - 2.f * gxx, 0.f));
        const float dyy = sqrtf(fmaxf(nyi + nyj - 2.f * gyy, 0.f));
        local += dxy - 0.5f * (dxx + dyy);
    }
#pragma unroll
    for (int off = 32; off; off >>= 1) local += __shfl_down(local, off);
    if ((t & 63) == 0) red[t >> 6] = local;
    __syncthreads();
    if (t == 0) {
        const float bl = red[0] + red[1] + red[2] + red[3];
        atomicAdd(acc, bl * (1.0f / (4096.0f * (float)NB)));
    }
}

// ---------------------------------------------------------------------------
// K3: cell-level — one block per shared gene s. Clouds: 64 points x 128 dims.
// fp32 vector-FMA path (exact).
// ---------------------------------------------------------------------------
__global__ __launch_bounds__(256) void k_cell(const float* __restrict__ X,
                                              const float* __restrict__ Y,
                                              float* __restrict__ acc) {
    const int s   = blockIdx.x;
    const int col = GENES - NSHARED + s;
    const int t   = threadIdx.x;

    __shared__ __align__(16) float lds[16384];    // 64 KB

#pragma unroll
    for (int k = 0; k < 32; ++k) {
        const int idx = t + 256 * k;              // = b*64 + n, 0..8191
        lds[idx]        = X[(size_t)idx * GENES + col];
        lds[8192 + idx] = Y[(size_t)idx * GENES + col];
    }
    __syncthreads();

    const int ti = t & 15, tj = t >> 4;
    const int i0 = ti << 2, j0 = tj << 2;
    float axy[4][4] = {{0}}, axx[4][4] = {{0}}, ayy[4][4] = {{0}};

#pragma unroll 4
    for (int bb = 0; bb < NB; ++bb) {
        const float4 xi4 = *(const float4*)(lds + bb * 64 + i0);
        const float4 xj4 = *(const float4*)(lds + bb * 64 + j0);
        const float4 yi4 = *(const float4*)(lds + 8192 + bb * 64 + i0);
        const float4 yj4 = *(const float4*)(lds + 8192 + bb * 64 + j0);
        const float* xi = &xi4.x;
        const float* xj = &xj4.x;
        const float* yi = &yi4.x;
        const float* yj = &yj4.x;
#pragma unroll
        for (int ii = 0; ii < 4; ++ii) {
#pragma unroll
            for (int jj = 0; jj < 4; ++jj) {
                axy[ii][jj] = fmaf(xi[ii], yj[jj], axy[ii][jj]);
                axx[ii][jj] = fmaf(xi[ii], xj[jj], axx[ii][jj]);
                ayy[ii][jj] = fmaf(yi[ii], yj[jj], ayy[ii][jj]);
            }
        }
    }
    __syncthreads();
#pragma unroll
    for (int ii = 0; ii < 4; ++ii) {
        float4 v;
        v.x = axy[ii][0]; v.y = axy[ii][1]; v.z = axy[ii][2]; v.w = axy[ii][3];
        *(float4*)(lds + 0 * 4096 + (i0 + ii) * 64 + j0) = v;
        v.x = axx[ii][0]; v.y = axx[ii][1]; v.z = axx[ii][2]; v.w = axx[ii][3];
        *(float4*)(lds + 1 * 4096 + (i0 + ii) * 64 + j0) = v;
        v.x = ayy[ii][0]; v.y = ayy[ii][1]; v.z = ayy[ii][2]; v.w = ayy[ii][3];
        *(float4*)(lds + 2 * 4096 + (i0 + ii) * 64 + j0) = v;
    }
    __syncthreads();

    float local = 0.f;
#pragma unroll
    for (int k = 0; k < 16; ++k) {
        const int e = t + 256 * k;
        const int i = e >> 6, j = e & 63;
        const float gxy = lds[e];
        const float gxx = lds[4096 + e];
        const float gyy = lds[8192 + e];
        const float nxi = lds[4096 + i * 65], nxj = lds[4096 + j * 65];
        const float nyi = lds[8192 + i * 65], nyj = lds[8192 + j * 65];
        const float dxy = sqrtf(fmaxf(nxi + nyj - 2.f * gxy, 0.f));
        const float dxx = sqrtf(fmaxf(nxi + nxj - 2.f * gxx, 0.f));
        const float dyy = sqrtf(fmaxf(nyi + nyj - 2.f * gyy, 0.f));
        local += dxy - 0.5f * (dxx + dyy);
    }
#pragma unroll
    for (int off = 32; off; off >>= 1) local += __shfl_down(local, off);
    __syncthreads();
    if ((t & 63) == 0) lds[t >> 6] = local;
    __syncthreads();
    if (t == 0) {
        const float bl = lds[0] + lds[1] + lds[2] + lds[3];
        atomicAdd(acc, bl * (1.0f / (4096.0f * (float)NSHARED)));
    }
}

__global__ void k_final(const float* __restrict__ acc, float* __restrict__ out) {
    out[0] = acc[0] + acc[1];
}

extern "C" void kernel_launch(void* const* d_in, const int* in_sizes, int n_in,
                              void* d_out, int out_size, void* d_ws, size_t ws_size,
                              hipStream_t stream) {
    const float* X = (const float*)d_in[0];
    const float* Y = (const float*)d_in[1];
    float* out = (float*)d_out;
    float* ws  = (float*)d_ws;

    // splitD=4 (round-11's splitD=8 regressed K2; occupancy proved not the lever)
    int splitD = 4;
    while (splitD > 1 &&
           ((size_t)GRAM_OFF + (size_t)splitD * NB * 3 * 4096) * sizeof(float) > ws_size)
        splitD >>= 1;
    const int chunks = (GENES + KC - 1) / KC;            // 20 at KC=256
    const int cper   = (chunks + splitD - 1) / splitD;   // 5 chunks per slice
    const int Dper   = cper * KC;                        // 1280

    float* acc   = ws;
    float* grams = ws + GRAM_OFF;

    hipLaunchKernelGGL(k_zero,           dim3(1),           dim3(64),  0, stream, ws);
    hipLaunchKernelGGL(k_gene_gram_mfma, dim3(NB * splitD), dim3(256), 0, stream,
                       X, Y, grams, splitD, Dper);
    hipLaunchKernelGGL(k_gene_dist,      dim3(NB),          dim3(256), 0, stream,
                       grams, acc + 0, splitD);
    hipLaunchKernelGGL(k_cell,           dim3(NSHARED),     dim3(256), 0, stream,
                       X, Y, acc + 1);
    hipLaunchKernelGGL(k_final,          dim3(1),           dim3(1),   0, stream, acc, out);
}

// Round 13
// 159.820 us; speedup vs baseline: 1.4057x; 1.2818x over previous
//
#include <hip/hip_runtime.h>
#include <math.h>

#define TOTAL   8192
#define GENES   5000
#define NDS     64          // points per cloud
#define NB      128         // TOTAL / NDS
#define NSHARED 128
#define KC      64          // K-chunk staged in LDS

// ws layout (floats): [0]=gene acc, [1]=cell acc, [32..35]=zero pad for tail,
// grams start at GRAM_OFF
#define GRAM_OFF 64

typedef __attribute__((ext_vector_type(8)))  short        short8;
typedef __attribute__((ext_vector_type(4)))  unsigned int uint4v;
typedef __attribute__((ext_vector_type(16))) float        f32x16;

typedef const __attribute__((address_space(1))) void* GPTR;
typedef __attribute__((address_space(3))) void*       LPTR;

// DMA global->LDS, 16B per lane, no VGPR transit (spill-proof staging)
#define GLOAD16(gp, lp) \
    __builtin_amdgcn_global_load_lds((GPTR)(gp), (LPTR)(lp), 16, 0, 0)

// ---- fp32 -> bf16 round-half-up, packed pairwise. hh-only MFMA verified
//      rounds 9-12: absmax ~0 vs 3.6e-2 threshold. ----
static __device__ inline unsigned int hpack2(float f0, float f1) {
    const unsigned int u0 = __builtin_bit_cast(unsigned int, f0) + 0x8000u;
    const unsigned int u1 = __builtin_bit_cast(unsigned int, f1) + 0x8000u;
    return (u1 & 0xFFFF0000u) | (u0 >> 16);
}
// read 8 consecutive logical fp32 (two 16B slots, XOR-swizzled) -> bf16x8
static __device__ inline short8 ldcvt_h(const float* base, int sw, int c0) {
    const float4 a = *(const float4*)(base + (((c0    ) ^ sw) << 2));
    const float4 b = *(const float4*)(base + (((c0 + 1) ^ sw) << 2));
    uint4v hv;
    hv[0] = hpack2(a.x, a.y); hv[1] = hpack2(a.z, a.w);
    hv[2] = hpack2(b.x, b.y); hv[3] = hpack2(b.z, b.w);
    return __builtin_bit_cast(short8, hv);
}

// ---------------------------------------------------------------------------
// Fused main kernel. Blocks [0, NSHARED): cell-level path (independent of
// gram results -> overlaps K1's stall-dominated streaming). Blocks
// [NSHARED, NSHARED + NB*splitD): gene-gram path (round-9 K1 verbatim:
// best-measured config; rounds 10-12 falsified scheduling/occupancy/
// granularity as levers — K1 is pinned ~128us by a per-CU MLP/latency cap).
// Both paths use the same 64KB smem and 256 threads.
// ---------------------------------------------------------------------------
__global__ __launch_bounds__(256, 2)
void k_main(const float* __restrict__ X, const float* __restrict__ Y,
            const float* __restrict__ zsrc, float* __restrict__ grams,
            float* __restrict__ acc, int splitD, int Dper) {
    __shared__ __align__(16) float smem[16384];   // 64 KB
    const int t = threadIdx.x;

    if ((int)blockIdx.x >= NSHARED) {
        // ================= gene-gram path =================
        const int blk = blockIdx.x - NSHARED;
        const int b = blk / splitD, c = blk % splitD;
        const int d0 = c * Dper;
        const int d1 = min(GENES, d0 + Dper);

        const float* __restrict__ xb = X + (size_t)b * NDS * GENES;
        const float* __restrict__ yb = Y + (size_t)b * NDS * GENES;

        float* sX = smem;                  // 2*NDS*KC = 8192 floats (32 KB)
        float* sY = smem + 2 * NDS * KC;   // 32 KB

        const int lane = t & 63;
        const int w    = t >> 6;               // wave 0..3
        const int qr   = w >> 1, qc = w & 1;   // 32x32 output quadrant
        const int lm   = lane & 31;
        const int kh2  = (lane >> 5) << 1;     // k-half offset in 16B slots

        const int mr  = (qr << 5) + lm;        // A-side row
        const int mc  = (qc << 5) + lm;        // B-side row (Gram col)
        const int swr = mr & 15, swc = mc & 15;

        // staging geometry: wave w stages rows [16w,16w+16), 4 instrs/array
        const int s16  = lane & 15;
        const int rsub = lane >> 4;
        const int rA = (w << 4) + rsub;
        const int rB = rA + 4, rC = rA + 8, rD = rA + 12;
        const int cA = (s16 ^ (rA & 15)) << 2;
        const int cB = (s16 ^ (rB & 15)) << 2;
        const int cC = (s16 ^ (rC & 15)) << 2;
        const int cD = (s16 ^ (rD & 15)) << 2;
        const float* gxA = xb + (size_t)rA * GENES + cA;
        const float* gxB = xb + (size_t)rB * GENES + cB;
        const float* gxC = xb + (size_t)rC * GENES + cC;
        const float* gxD = xb + (size_t)rD * GENES + cD;
        const float* gyA = yb + (size_t)rA * GENES + cA;
        const float* gyB = yb + (size_t)rB * GENES + cB;
        const float* gyC = yb + (size_t)rC * GENES + cC;
        const float* gyD = yb + (size_t)rD * GENES + cD;
        const int lA = ((w << 4) + 0) * KC;
        const int lB = lA + 4 * KC, lC = lA + 8 * KC, lD = lA + 12 * KC;

#define STAGEBUF(bofs, dd) do {                                               \
    const float* pxA = ((dd) + cA + 4 <= d1) ? gxA + (dd) : zsrc;             \
    const float* pxB = ((dd) + cB + 4 <= d1) ? gxB + (dd) : zsrc;             \
    const float* pxC = ((dd) + cC + 4 <= d1) ? gxC + (dd) : zsrc;             \
    const float* pxD = ((dd) + cD + 4 <= d1) ? gxD + (dd) : zsrc;             \
    const float* pyA = ((dd) + cA + 4 <= d1) ? gyA + (dd) : zsrc;             \
    const float* pyB = ((dd) + cB + 4 <= d1) ? gyB + (dd) : zsrc;             \
    const float* pyC = ((dd) + cC + 4 <= d1) ? gyC + (dd) : zsrc;             \
    const float* pyD = ((dd) + cD + 4 <= d1) ? gyD + (dd) : zsrc;             \
    GLOAD16(pxA, sX + (bofs) + lA);                                           \
    GLOAD16(pxB, sX + (bofs) + lB);                                           \
    GLOAD16(pxC, sX + (bofs) + lC);                                           \
    GLOAD16(pxD, sX + (bofs) + lD);                                           \
    GLOAD16(pyA, sY + (bofs) + lA);                                           \
    GLOAD16(pyB, sY + (bofs) + lB);                                           \
    GLOAD16(pyC, sY + (bofs) + lC);                                           \
    GLOAD16(pyD, sY + (bofs) + lD);                                           \
} while (0)

        f32x16 axy = {0,0,0,0,0,0,0,0,0,0,0,0,0,0,0,0};
        f32x16 axx = {0,0,0,0,0,0,0,0,0,0,0,0,0,0,0,0};
        f32x16 ayy = {0,0,0,0,0,0,0,0,0,0,0,0,0,0,0,0};

        const int nchunks = (d1 - d0 + KC - 1) / KC;

        STAGEBUF(0, d0);          // prologue: chunk 0 -> buf 0
        __syncthreads();          // vmcnt(0) + barrier: buf 0 ready

        for (int ci = 0; ci < nchunks; ++ci) {
            const int bofs = (ci & 1) * (NDS * KC);
            if (ci + 1 < nchunks)
                STAGEBUF(((ci + 1) & 1) * (NDS * KC), d0 + (ci + 1) * KC);

            const float* xrow = sX + bofs + mr * KC;
            const float* yrow = sY + bofs + mr * KC;
            const float* xcol = sX + bofs + mc * KC;
            const float* ycol = sY + bofs + mc * KC;
#pragma unroll
            for (int ks = 0; ks < 4; ++ks) {
                const int c0 = (ks << 2) + kh2;
                const short8 xr = ldcvt_h(xrow, swr, c0);
                const short8 yr = ldcvt_h(yrow, swr, c0);
                const short8 xc = ldcvt_h(xcol, swc, c0);
                const short8 yc = ldcvt_h(ycol, swc, c0);
                axy = __builtin_amdgcn_mfma_f32_32x32x16_bf16(xr, yc, axy, 0, 0, 0);
                axx = __builtin_amdgcn_mfma_f32_32x32x16_bf16(xr, xc, axx, 0, 0, 0);
                ayy = __builtin_amdgcn_mfma_f32_32x32x16_bf16(yr, yc, ayy, 0, 0, 0);
            }
            __syncthreads();      // drains stage loads + buffer handoff
        }
#undef STAGEBUF

        // writeout: verified 32x32 C/D layout: col=lane&31,
        // row=(reg&3)+8*(reg>>2)+4*(lane>>5)
        float* g = grams + (size_t)(b * splitD + c) * 3 * 4096;
        const int col = (qc << 5) + lm;
#pragma unroll
        for (int r = 0; r < 16; ++r) {
            const int row = (qr << 5) + (r & 3) + ((r >> 2) << 3) + ((lane >> 5) << 2);
            g[0 * 4096 + row * 64 + col] = axy[r];
            g[1 * 4096 + row * 64 + col] = axx[r];
            g[2 * 4096 + row * 64 + col] = ayy[r];
        }
        return;
    }

    // ================= cell-level path (one block per shared gene) =========
    {
        const int s   = blockIdx.x;
        const int col = GENES - NSHARED + s;
        float* lds = smem;                    // 16384 floats

#pragma unroll
        for (int k = 0; k < 32; ++k) {
            const int idx = t + 256 * k;      // = b*64 + n, 0..8191
            lds[idx]        = X[(size_t)idx * GENES + col];
            lds[8192 + idx] = Y[(size_t)idx * GENES + col];
        }
        __syncthreads();

        const int ti = t & 15, tj = t >> 4;
        const int i0 = ti << 2, j0 = tj << 2;
        float axy[4][4] = {{0}}, axx[4][4] = {{0}}, ayy[4][4] = {{0}};

#pragma unroll 4
        for (int bb = 0; bb < NB; ++bb) {
            const float4 xi4 = *(const float4*)(lds + bb * 64 + i0);
            const float4 xj4 = *(const float4*)(lds + bb * 64 + j0);
            const float4 yi4 = *(const float4*)(lds + 8192 + bb * 64 + i0);
            const float4 yj4 = *(const float4*)(lds + 8192 + bb * 64 + j0);
            const float* xi = &xi4.x;
            const float* xj = &xj4.x;
            const float* yi = &yi4.x;
            const float* yj = &yj4.x;
#pragma unroll
            for (int ii = 0; ii < 4; ++ii) {
#pragma unroll
                for (int jj = 0; jj < 4; ++jj) {
                    axy[ii][jj] = fmaf(xi[ii], yj[jj], axy[ii][jj]);
                    axx[ii][jj] = fmaf(xi[ii], xj[jj], axx[ii][jj]);
                    ayy[ii][jj] = fmaf(yi[ii], yj[jj], ayy[ii][jj]);
                }
            }
        }
        __syncthreads();
#pragma unroll
        for (int ii = 0; ii < 4; ++ii) {
            float4 v;
            v.x = axy[ii][0]; v.y = axy[ii][1]; v.z = axy[ii][2]; v.w = axy[ii][3];
            *(float4*)(lds + 0 * 4096 + (i0 + ii) * 64 + j0) = v;
            v.x = axx[ii][0]; v.y = axx[ii][1]; v.z = axx[ii][2]; v.w = axx[ii][3];
            *(float4*)(lds + 1 * 4096 + (i0 + ii) * 64 + j0) = v;
            v.x = ayy[ii][0]; v.y = ayy[ii][1]; v.z = ayy[ii][2]; v.w = ayy[ii][3];
            *(float4*)(lds + 2 * 4096 + (i0 + ii) * 64 + j0) = v;
        }
        __syncthreads();

        float local = 0.f;
#pragma unroll
        for (int k = 0; k < 16; ++k) {
            const int e = t + 256 * k;
            const int i = e >> 6, j = e & 63;
            const float gxy = lds[e];
            const float gxx = lds[4096 + e];
            const float gyy = lds[8192 + e];
            const float nxi = lds[4096 + i * 65], nxj = lds[4096 + j * 65];
            const float nyi = lds[8192 + i * 65], nyj = lds[8192 + j * 65];
            const float dxy = sqrtf(fmaxf(nxi + nyj - 2.f * gxy, 0.f));
            const float dxx = sqrtf(fmaxf(nxi + nxj - 2.f * gxx, 0.f));
            const float dyy = sqrtf(fmaxf(nyi + nyj - 2.f * gyy, 0.f));
            local += dxy - 0.5f * (dxx + dyy);
        }
#pragma unroll
        for (int off = 32; off; off >>= 1) local += __shfl_down(local, off);
        __syncthreads();
        if ((t & 63) == 0) lds[t >> 6] = local;
        __syncthreads();
        if (t == 0) {
            const float bl = lds[0] + lds[1] + lds[2] + lds[3];
            atomicAdd(acc + 1, bl * (1.0f / (4096.0f * (float)NSHARED)));
        }
    }
}

// ---------------------------------------------------------------------------
// K2: per batch — reduce Gram partials, distances, mean, accumulate.
// ---------------------------------------------------------------------------
__global__ __launch_bounds__(256) void k_gene_dist(const float* __restrict__ grams,
                                                   float* __restrict__ acc,
                                                   int splitD) {
    const int b = blockIdx.x, t = threadIdx.x;
    __shared__ __align__(16) float G[3 * 4096];   // 48 KB
    __shared__ float red[4];

    for (int m = 0; m < 3; ++m) {
#pragma unroll
        for (int k = 0; k < 16; ++k) {
            const int e = t + 256 * k;
            float s = 0.f;
            for (int c = 0; c < splitD; ++c)
                s += grams[((size_t)(b * splitD + c) * 3 + m) * 4096 + e];
            G[m * 4096 + e] = s;
        }
    }
    __syncthreads();

    float local = 0.f;
#pragma unroll
    for (int k = 0; k < 16; ++k) {
        const int e = t + 256 * k;
        const int i = e >> 6, j = e & 63;
        const float gxy = G[e];
        const float gxx = G[4096 + e];
        const float gyy = G[8192 + e];
        const float nxi = G[4096 + i * 65], nxj = G[4096 + j * 65];
        const float nyi = G[8192 + i * 65], nyj = G[8192 + j * 65];
        const float dxy = sqrtf(fmaxf(nxi + nyj - 2.f * gxy, 0.f));
        const float dxx = sqrtf(fmaxf(nxi + nxj - 2.f * gxx, 0.f));
        const float dyy = sqrtf(fmaxf(nyi + nyj - 2.f * gyy, 0.f));
        local += dxy - 0.5f * (dxx + dyy);
    }
#pragma unroll
    for (int off = 32; off; off >>= 1) local += __shfl_down(local, off);
    if ((t & 63) == 0) red[t >> 6] = local;
    __syncthreads();
    if (t == 0) {
        const float bl = red[0] + red[1] + red[2] + red[3];
        atomicAdd(acc, bl * (1.0f / (4096.0f * (float)NB)));
    }
}

__global__ void k_final(const float* __restrict__ acc, float* __restrict__ out) {
    out[0] = acc[0] + acc[1];
}

extern "C" void kernel_launch(void* const* d_in, const int* in_sizes, int n_in,
                              void* d_out, int out_size, void* d_ws, size_t ws_size,
                              hipStream_t stream) {
    const float* X = (const float*)d_in[0];
    const float* Y = (const float*)d_in[1];
    float* out = (float*)d_out;
    float* ws  = (float*)d_ws;

    int splitD = 4;
    while (splitD > 1 &&
           ((size_t)GRAM_OFF + (size_t)splitD * NB * 3 * 4096) * sizeof(float) > ws_size)
        splitD >>= 1;
    const int chunks = (GENES + KC - 1) / KC;            // 79
    const int cper   = (chunks + splitD - 1) / splitD;   // chunks per slice
    const int Dper   = cper * KC;                        // multiple of KC

    float* acc   = ws;
    float* zsrc  = ws + 32;          // 16B of zeros (memset covers [0,64))
    float* grams = ws + GRAM_OFF;

    // zero acc + zsrc region (replaces k_zero launch)
    hipMemsetAsync(ws, 0, GRAM_OFF * sizeof(float), stream);
    // fused: cell blocks first (co-resident from t=0, hide under gram stalls)
    hipLaunchKernelGGL(k_main, dim3(NSHARED + NB * splitD), dim3(256), 0, stream,
                       X, Y, zsrc, grams, acc, splitD, Dper);
    hipLaunchKernelGGL(k_gene_dist, dim3(NB), dim3(256), 0, stream,
                       grams, acc + 0, splitD);
    hipLaunchKernelGGL(k_final, dim3(1), dim3(1), 0, stream, acc, out);
}